// Round 1
// baseline (51690.253 us; speedup 1.0000x reference)
//
#include <hip/hip_runtime.h>
#include <hip/hip_bf16.h>

#define BB 1024
#define TT 512
#define II 128
#define HH 64
#define G4 256   // 4*H
#define EE 128
#define CC 100
#define NB 4     // batch rows per block; NB*HH == 256 threads exactly

__device__ __forceinline__ float sigm(float v) { return 1.f / (1.f + __expf(-v)); }
__device__ __forceinline__ float tanh_f(float v) {
    v = fminf(fmaxf(v, -15.f), 15.f);   // avoid inf/inf NaN; tanh(15) == 1 to fp32
    float e = __expf(2.f * v);
    return (e - 1.f) / (e + 1.f);
}

// Persistent fused 2-layer LSTM. One block per NB batch rows, full T loop inside.
// Thread g (0..255) owns gate row g of BOTH layers; weights live in VGPRs.
__global__ __launch_bounds__(256, 1)
void lstm2_persistent(const float* __restrict__ x,
                      const float* __restrict__ Wih0, const float* __restrict__ Whh0,
                      const float* __restrict__ bih0, const float* __restrict__ bhh0,
                      const float* __restrict__ Wih1, const float* __restrict__ Whh1,
                      const float* __restrict__ bih1, const float* __restrict__ bhh1,
                      float* __restrict__ hlast)
{
    __shared__ float xs[NB][II];     // current x tile
    __shared__ float h0s[NB][HH];    // layer-0 hidden
    __shared__ float h1s[NB][HH];    // layer-1 hidden
    __shared__ float a0[NB][G4];     // activated gates, layer 0
    __shared__ float a1[NB][G4];     // activated gates, layer 1

    const int g  = threadIdx.x;          // gate row 0..255 (i:0-63 f:64-127 g:128-191 o:192-255)
    const int b0 = blockIdx.x * NB;

    // ---- weights into registers (persist across all 512 steps) ----
    float wih0[II], whh0[HH], wih1[HH], whh1[HH];
    #pragma unroll
    for (int k = 0; k < II; ++k) wih0[k] = Wih0[g * II + k];
    #pragma unroll
    for (int k = 0; k < HH; ++k) whh0[k] = Whh0[g * HH + k];
    #pragma unroll
    for (int k = 0; k < HH; ++k) wih1[k] = Wih1[g * HH + k];
    #pragma unroll
    for (int k = 0; k < HH; ++k) whh1[k] = Whh1[g * HH + k];
    const float bs0 = bih0[g] + bhh0[g];
    const float bs1 = bih1[g] + bhh1[g];

    // cell ownership for the elementwise update: thread g -> (batch cb, cell cj)
    const int cb = g >> 6;
    const int cj = g & 63;
    float c0 = 0.f, c1 = 0.f;
    h0s[cb][cj] = 0.f;
    h1s[cb][cj] = 0.f;

    // x staging: thread loads 2 consecutive floats of row lr each step (coalesced)
    const int lr = g >> 6;
    const int lc = (g & 63) * 2;
    const float* xrow = x + ((size_t)(b0 + lr) * TT) * II + lc;

    float2 pre = *(const float2*)(xrow);   // prefetch t = 0
    const bool gate_tanh = (g >= 128 && g < 192);

    for (int t = 0; t < TT; ++t) {
        *(float2*)&xs[lr][lc] = pre;
        if (t + 1 < TT) pre = *(const float2*)(xrow + (size_t)(t + 1) * II);
        __syncthreads();

        // ---- layer-0 gate GEMV: z = bs0 + Wih0[g,:]·x[b] + Whh0[g,:]·h0[b] ----
        float z[NB];
        #pragma unroll
        for (int b = 0; b < NB; ++b) z[b] = bs0;
        #pragma unroll
        for (int b = 0; b < NB; ++b) {
            const float4* xv = (const float4*)xs[b];
            #pragma unroll
            for (int k = 0; k < II / 4; ++k) {
                float4 v = xv[k];
                z[b] += wih0[4*k+0]*v.x + wih0[4*k+1]*v.y + wih0[4*k+2]*v.z + wih0[4*k+3]*v.w;
            }
            const float4* hv = (const float4*)h0s[b];
            #pragma unroll
            for (int k = 0; k < HH / 4; ++k) {
                float4 v = hv[k];
                z[b] += whh0[4*k+0]*v.x + whh0[4*k+1]*v.y + whh0[4*k+2]*v.z + whh0[4*k+3]*v.w;
            }
        }
        #pragma unroll
        for (int b = 0; b < NB; ++b)
            a0[b][g] = gate_tanh ? tanh_f(z[b]) : sigm(z[b]);
        __syncthreads();

        // ---- layer-0 cell/hidden update ----
        {
            float gi = a0[cb][cj], gf = a0[cb][64 + cj], gg = a0[cb][128 + cj], go = a0[cb][192 + cj];
            c0 = gf * c0 + gi * gg;
            h0s[cb][cj] = go * tanh_f(c0);
        }
        __syncthreads();

        // ---- layer-1 gate GEMV: z = bs1 + Wih1[g,:]·h0[b] + Whh1[g,:]·h1[b] ----
        #pragma unroll
        for (int b = 0; b < NB; ++b) z[b] = bs1;
        #pragma unroll
        for (int b = 0; b < NB; ++b) {
            const float4* hv0 = (const float4*)h0s[b];
            #pragma unroll
            for (int k = 0; k < HH / 4; ++k) {
                float4 v = hv0[k];
                z[b] += wih1[4*k+0]*v.x + wih1[4*k+1]*v.y + wih1[4*k+2]*v.z + wih1[4*k+3]*v.w;
            }
            const float4* hv1 = (const float4*)h1s[b];
            #pragma unroll
            for (int k = 0; k < HH / 4; ++k) {
                float4 v = hv1[k];
                z[b] += whh1[4*k+0]*v.x + whh1[4*k+1]*v.y + whh1[4*k+2]*v.z + whh1[4*k+3]*v.w;
            }
        }
        #pragma unroll
        for (int b = 0; b < NB; ++b)
            a1[b][g] = gate_tanh ? tanh_f(z[b]) : sigm(z[b]);
        __syncthreads();

        // ---- layer-1 cell/hidden update ----
        {
            float gi = a1[cb][cj], gf = a1[cb][64 + cj], gg = a1[cb][128 + cj], go = a1[cb][192 + cj];
            c1 = gf * c1 + gi * gg;
            h1s[cb][cj] = go * tanh_f(c1);
        }
        __syncthreads();
    }

    hlast[(size_t)(b0 + cb) * HH + cj] = h1s[cb][cj];
}

// MLP head: one block per batch row. relu(hW_p^T+b) -> relu(.W_1^T+b) -> .W_2^T+b
__global__ __launch_bounds__(128, 4)
void head_kernel(const float* __restrict__ hlast,
                 const float* __restrict__ Wp, const float* __restrict__ bp,
                 const float* __restrict__ W1, const float* __restrict__ b1,
                 const float* __restrict__ W2, const float* __restrict__ b2,
                 float* __restrict__ out)
{
    __shared__ float hv[HH];
    __shared__ float emb[EE];
    __shared__ float hid[EE];
    const int b = blockIdx.x;
    const int e = threadIdx.x;   // 0..127
    if (e < HH) hv[e] = hlast[(size_t)b * HH + e];
    __syncthreads();
    float z = bp[e];
    #pragma unroll
    for (int j = 0; j < HH; ++j) z += Wp[e * HH + j] * hv[j];
    emb[e] = fmaxf(z, 0.f);
    __syncthreads();
    z = b1[e];
    #pragma unroll
    for (int j = 0; j < EE; ++j) z += W1[e * EE + j] * emb[j];
    hid[e] = fmaxf(z, 0.f);
    __syncthreads();
    if (e < CC) {
        z = b2[e];
        #pragma unroll
        for (int j = 0; j < EE; ++j) z += W2[e * EE + j] * hid[j];
        out[(size_t)b * CC + e] = z;
    }
}

extern "C" void kernel_launch(void* const* d_in, const int* in_sizes, int n_in,
                              void* d_out, int out_size, void* d_ws, size_t ws_size,
                              hipStream_t stream)
{
    const float* x    = (const float*)d_in[0];
    const float* Wih0 = (const float*)d_in[1];
    const float* Whh0 = (const float*)d_in[2];
    const float* bih0 = (const float*)d_in[3];
    const float* bhh0 = (const float*)d_in[4];
    const float* Wih1 = (const float*)d_in[5];
    const float* Whh1 = (const float*)d_in[6];
    const float* bih1 = (const float*)d_in[7];
    const float* bhh1 = (const float*)d_in[8];
    const float* Wp   = (const float*)d_in[9];
    const float* bp   = (const float*)d_in[10];
    const float* W1   = (const float*)d_in[11];
    const float* b1   = (const float*)d_in[12];
    const float* W2   = (const float*)d_in[13];
    const float* b2   = (const float*)d_in[14];

    float* hlast = (float*)d_ws;           // 1024*64 fp32 = 256 KB
    float* out   = (float*)d_out;          // [1024, 100] fp32

    lstm2_persistent<<<BB / NB, 256, 0, stream>>>(x, Wih0, Whh0, bih0, bhh0,
                                                  Wih1, Whh1, bih1, bhh1, hlast);
    head_kernel<<<BB, EE, 0, stream>>>(hlast, Wp, bp, W1, b1, W2, b2, out);
}

// Round 2
// 2475.108 us; speedup vs baseline: 20.8840x; 20.8840x over previous
//
#include <hip/hip_runtime.h>
#include <hip/hip_bf16.h>

#define BB 1024
#define TT 512
#define II 128
#define HH 64
#define G4 256   // 4*H
#define EE 128
#define CC 100
#define NB 4     // batch rows per block; 256 blocks = 1 per CU
#define NTH 512  // 2-way split-K over gate rows: thread = (p, g)

__device__ __forceinline__ float sigm(float v) { return 1.f / (1.f + __expf(-v)); }
__device__ __forceinline__ float tanh_f(float v) {
    v = fminf(fmaxf(v, -15.f), 15.f);   // avoid inf/inf NaN
    float e = __expf(2.f * v);
    return (e - 1.f) / (e + 1.f);
}

// Persistent fused 2-layer LSTM, split-K edition.
// Round-1 lesson: 320 weight floats/thread spilled to scratch (84 GB HBM traffic).
// Here thread (p, g) owns the p-th K-half of gate row g of all four weight
// matrices: 64+32+32+32 = 160 floats -> ~200 VGPRs, no spill.
__global__ __launch_bounds__(NTH, 1)
void lstm2_persistent(const float* __restrict__ x,
                      const float* __restrict__ Wih0, const float* __restrict__ Whh0,
                      const float* __restrict__ bih0, const float* __restrict__ bhh0,
                      const float* __restrict__ Wih1, const float* __restrict__ Whh1,
                      const float* __restrict__ bih1, const float* __restrict__ bhh1,
                      float* __restrict__ hlast)
{
    __shared__ float xs[2][NB][II];      // double-buffered x tile (4 KB)
    __shared__ float h0s[NB][HH];        // layer-0 hidden
    __shared__ float h1s[NB][HH];        // layer-1 hidden
    __shared__ float zp0[2][NB][G4];     // layer-0 split-K partials (8 KB)
    __shared__ float zp1[2][NB][G4];     // layer-1 split-K partials (8 KB)
    __shared__ float bs0s[G4], bs1s[G4]; // folded biases

    const int tid = threadIdx.x;
    const int p   = tid >> 8;            // K-half (waves 0-3: p=0, waves 4-7: p=1)
    const int g   = tid & 255;           // gate row (i:0-63 f:64-127 g:128-191 o:192-255)
    const int b0  = blockIdx.x * NB;

    // ---- half weight rows into registers (160 floats, persists all 512 steps) ----
    float4 w0[II/8], wh0[HH/8], w1[HH/8], wh1[HH/8];   // 16 + 8 + 8 + 8 float4
    {
        const float4* s0 = (const float4*)(Wih0 + (size_t)g * II + p * (II/2));
        #pragma unroll
        for (int k = 0; k < II/8; ++k) w0[k] = s0[k];
        const float4* s1 = (const float4*)(Whh0 + (size_t)g * HH + p * (HH/2));
        #pragma unroll
        for (int k = 0; k < HH/8; ++k) wh0[k] = s1[k];
        const float4* s2 = (const float4*)(Wih1 + (size_t)g * HH + p * (HH/2));
        #pragma unroll
        for (int k = 0; k < HH/8; ++k) w1[k] = s2[k];
        const float4* s3 = (const float4*)(Whh1 + (size_t)g * HH + p * (HH/2));
        #pragma unroll
        for (int k = 0; k < HH/8; ++k) wh1[k] = s3[k];
    }

    if (tid < G4) {
        bs0s[tid] = bih0[tid] + bhh0[tid];
        bs1s[tid] = bih1[tid] + bhh1[tid];
        h0s[tid >> 6][tid & 63] = 0.f;
        h1s[tid >> 6][tid & 63] = 0.f;
    }

    // x staging: thread (lr, lc) loads 1 float/step, coalesced; 2-step prefetch
    const int lr = tid >> 7;             // 0..3
    const int lc = tid & 127;            // 0..127
    const float* xrow = x + ((size_t)(b0 + lr) * TT) * II + lc;
    xs[0][lr][lc] = xrow[0];
    float pre = xrow[II];                // t = 1

    // combine-stage ownership (tid < 256): cell state lives in these registers
    const int cb = tid >> 6, cj = tid & 63;
    float c0 = 0.f, c1 = 0.f;

    __syncthreads();

    // Hazard analysis for the 3-barrier step (zp0/zp1 are separate buffers, xs
    // is double-buffered): every writer/reader pair crosses >=1 barrier; stage-4
    // needs no trailing barrier because next-step stage-1 touches only
    // zp0/xs/h0s, none of which stage-4 reads or writes.
    for (int t = 0; t < TT; ++t) {
        const int cur = t & 1, nxt = (t + 1) & 1;

        // ---- stage 1: layer-0 partial GEMV (reads xs[cur], h0s; writes zp0) ----
        float z[NB];
        #pragma unroll
        for (int b = 0; b < NB; ++b) {
            float acc = 0.f;
            const float4* xv = (const float4*)&xs[cur][b][p * (II/2)];
            #pragma unroll
            for (int k = 0; k < II/8; ++k) {
                float4 v = xv[k];   // wave-uniform address -> LDS broadcast
                acc += w0[k].x*v.x + w0[k].y*v.y + w0[k].z*v.z + w0[k].w*v.w;
            }
            const float4* hv = (const float4*)&h0s[b][p * (HH/2)];
            #pragma unroll
            for (int k = 0; k < HH/8; ++k) {
                float4 v = hv[k];
                acc += wh0[k].x*v.x + wh0[k].y*v.y + wh0[k].z*v.z + wh0[k].w*v.w;
            }
            z[b] = acc;
        }
        #pragma unroll
        for (int b = 0; b < NB; ++b) zp0[p][b][g] = z[b];
        __syncthreads();   // bar1

        // ---- stage 2: layer-0 combine + activation + cell update (tid<256) ----
        if (tid < G4) {
            float zi = zp0[0][cb][cj]       + zp0[1][cb][cj]       + bs0s[cj];
            float zf = zp0[0][cb][ 64 + cj] + zp0[1][cb][ 64 + cj] + bs0s[ 64 + cj];
            float zg = zp0[0][cb][128 + cj] + zp0[1][cb][128 + cj] + bs0s[128 + cj];
            float zo = zp0[0][cb][192 + cj] + zp0[1][cb][192 + cj] + bs0s[192 + cj];
            float gi = sigm(zi), gf = sigm(zf), gg = tanh_f(zg), go = sigm(zo);
            c0 = gf * c0 + gi * gg;
            h0s[cb][cj] = go * tanh_f(c0);
        }
        __syncthreads();   // bar2

        // ---- stage 3: layer-1 partial GEMV + x staging for t+1 ----
        #pragma unroll
        for (int b = 0; b < NB; ++b) {
            float acc = 0.f;
            const float4* hv0 = (const float4*)&h0s[b][p * (HH/2)];
            #pragma unroll
            for (int k = 0; k < HH/8; ++k) {
                float4 v = hv0[k];
                acc += w1[k].x*v.x + w1[k].y*v.y + w1[k].z*v.z + w1[k].w*v.w;
            }
            const float4* hv1 = (const float4*)&h1s[b][p * (HH/2)];
            #pragma unroll
            for (int k = 0; k < HH/8; ++k) {
                float4 v = hv1[k];
                acc += wh1[k].x*v.x + wh1[k].y*v.y + wh1[k].z*v.z + wh1[k].w*v.w;
            }
            z[b] = acc;
        }
        #pragma unroll
        for (int b = 0; b < NB; ++b) zp1[p][b][g] = z[b];
        xs[nxt][lr][lc] = pre;
        {
            int tn = (t + 2 < TT) ? t + 2 : TT - 1;
            pre = xrow[(size_t)tn * II];
        }
        __syncthreads();   // bar3

        // ---- stage 4: layer-1 combine + cell update (tid<256), no barrier ----
        if (tid < G4) {
            float zi = zp1[0][cb][cj]       + zp1[1][cb][cj]       + bs1s[cj];
            float zf = zp1[0][cb][ 64 + cj] + zp1[1][cb][ 64 + cj] + bs1s[ 64 + cj];
            float zg = zp1[0][cb][128 + cj] + zp1[1][cb][128 + cj] + bs1s[128 + cj];
            float zo = zp1[0][cb][192 + cj] + zp1[1][cb][192 + cj] + bs1s[192 + cj];
            float gi = sigm(zi), gf = sigm(zf), gg = tanh_f(zg), go = sigm(zo);
            c1 = gf * c1 + gi * gg;
            h1s[cb][cj] = go * tanh_f(c1);
        }
    }

    // stage-4 thread wrote h1s[cb][cj] itself -> read-own-write, no barrier
    if (tid < G4) hlast[(size_t)(b0 + cb) * HH + cj] = h1s[cb][cj];
}

// MLP head: one block per batch row. relu(hW_p^T+b) -> relu(.W_1^T+b) -> .W_2^T+b
__global__ __launch_bounds__(128, 4)
void head_kernel(const float* __restrict__ hlast,
                 const float* __restrict__ Wp, const float* __restrict__ bp,
                 const float* __restrict__ W1, const float* __restrict__ b1,
                 const float* __restrict__ W2, const float* __restrict__ b2,
                 float* __restrict__ out)
{
    __shared__ float hv[HH];
    __shared__ float emb[EE];
    __shared__ float hid[EE];
    const int b = blockIdx.x;
    const int e = threadIdx.x;   // 0..127
    if (e < HH) hv[e] = hlast[(size_t)b * HH + e];
    __syncthreads();
    float z = bp[e];
    #pragma unroll
    for (int j = 0; j < HH; ++j) z += Wp[e * HH + j] * hv[j];
    emb[e] = fmaxf(z, 0.f);
    __syncthreads();
    z = b1[e];
    #pragma unroll
    for (int j = 0; j < EE; ++j) z += W1[e * EE + j] * emb[j];
    hid[e] = fmaxf(z, 0.f);
    __syncthreads();
    if (e < CC) {
        z = b2[e];
        #pragma unroll
        for (int j = 0; j < EE; ++j) z += W2[e * EE + j] * hid[j];
        out[(size_t)b * CC + e] = z;
    }
}

extern "C" void kernel_launch(void* const* d_in, const int* in_sizes, int n_in,
                              void* d_out, int out_size, void* d_ws, size_t ws_size,
                              hipStream_t stream)
{
    const float* x    = (const float*)d_in[0];
    const float* Wih0 = (const float*)d_in[1];
    const float* Whh0 = (const float*)d_in[2];
    const float* bih0 = (const float*)d_in[3];
    const float* bhh0 = (const float*)d_in[4];
    const float* Wih1 = (const float*)d_in[5];
    const float* Whh1 = (const float*)d_in[6];
    const float* bih1 = (const float*)d_in[7];
    const float* bhh1 = (const float*)d_in[8];
    const float* Wp   = (const float*)d_in[9];
    const float* bp   = (const float*)d_in[10];
    const float* W1   = (const float*)d_in[11];
    const float* b1   = (const float*)d_in[12];
    const float* W2   = (const float*)d_in[13];
    const float* b2   = (const float*)d_in[14];

    float* hlast = (float*)d_ws;           // 1024*64 fp32 = 256 KB
    float* out   = (float*)d_out;          // [1024, 100] fp32

    lstm2_persistent<<<BB / NB, NTH, 0, stream>>>(x, Wih0, Whh0, bih0, bhh0,
                                                  Wih1, Whh1, bih1, bhh1, hlast);
    head_kernel<<<BB, EE, 0, stream>>>(hlast, Wp, bp, W1, b1, W2, b2, out);
}

// Round 3
// 1539.111 us; speedup vs baseline: 33.5845x; 1.6081x over previous
//
#include <hip/hip_runtime.h>
#include <hip/hip_bf16.h>

#define BB 1024
#define TT 512
#define II 128
#define HH 64
#define G4 256   // 4*H
#define EE 128
#define CC 100
#define NB 4     // batch rows per block; 256 blocks = 1 per CU
#define NTH 512

typedef float f2 __attribute__((ext_vector_type(2)));
typedef float f4 __attribute__((ext_vector_type(4)));

__device__ __forceinline__ float sigm(float v) { return 1.f / (1.f + __expf(-v)); }
__device__ __forceinline__ float tanh_f(float v) {
    v = fminf(fmaxf(v, -15.f), 15.f);   // avoid inf/inf NaN
    float e = __expf(2.f * v);
    return (e - 1.f) / (e + 1.f);
}

// Persistent fused 2-layer LSTM.
// Round-2 lesson: VGPR_Count=104 proved the 160 weight floats were NOT in
// arch VGPRs (accvgpr/remat shuffle -> 3x VALU inflation). This version:
//  - thread (q,r) owns gate rows {r, r+128} and K-quarter q  (2 rows/thread
//    halves LDS broadcast reads per FMA)
//  - weights as float2 vectors -> v_pk_fma_f32 (halves FMA issue)
//  - asm "+v" pin inside the t-loop forces weights into arch VGPRs
__global__ __launch_bounds__(NTH, 2)
void lstm2_persistent(const float* __restrict__ x,
                      const float* __restrict__ Wih0, const float* __restrict__ Whh0,
                      const float* __restrict__ bih0, const float* __restrict__ bhh0,
                      const float* __restrict__ Wih1, const float* __restrict__ Whh1,
                      const float* __restrict__ bih1, const float* __restrict__ bhh1,
                      float* __restrict__ hlast)
{
    __shared__ float xs[2][NB][II];      // double-buffered x tile (4 KB)
    __shared__ float h0s[NB][HH];        // layer-0 hidden
    __shared__ float h1s[NB][HH];        // layer-1 hidden
    __shared__ float zp0[4][NB][G4];     // layer-0 split-K partials (16 KB)
    __shared__ float zp1[4][NB][G4];     // layer-1 split-K partials (16 KB)
    __shared__ float bs0s[G4], bs1s[G4]; // folded biases

    const int tid = threadIdx.x;
    const int q   = tid >> 7;            // K-quarter 0..3 (wave-uniform)
    const int r   = tid & 127;           // row-pair id: owns gate rows r, r+128
    const int b0  = blockIdx.x * NB;

    // ---- weight fragments: 80 float2 = 160 floats, register-resident ----
    f2 w0a[16], w0b[16];   // Wih0 rows r / r+128, cols [q*32, q*32+32)
    f2 h0a[8],  h0b[8];    // Whh0 rows r / r+128, cols [q*16, q*16+16)
    f2 u1a[8],  u1b[8];    // Wih1 rows r / r+128, cols [q*16, q*16+16)
    f2 v1a[8],  v1b[8];    // Whh1 rows r / r+128, cols [q*16, q*16+16)

#define LOADW(dst, src, n4)                                          \
    do {                                                             \
        const f4* _s = (const f4*)(src);                             \
        _Pragma("unroll")                                            \
        for (int k = 0; k < (n4); ++k) {                             \
            f4 t = _s[k];                                            \
            dst[2*k]   = (f2){t.x, t.y};                             \
            dst[2*k+1] = (f2){t.z, t.w};                             \
        }                                                            \
    } while (0)

    LOADW(w0a, Wih0 + (size_t)r         * II + q * 32, 8);
    LOADW(w0b, Wih0 + (size_t)(r + 128) * II + q * 32, 8);
    LOADW(h0a, Whh0 + (size_t)r         * HH + q * 16, 4);
    LOADW(h0b, Whh0 + (size_t)(r + 128) * HH + q * 16, 4);
    LOADW(u1a, Wih1 + (size_t)r         * HH + q * 16, 4);
    LOADW(u1b, Wih1 + (size_t)(r + 128) * HH + q * 16, 4);
    LOADW(v1a, Whh1 + (size_t)r         * HH + q * 16, 4);
    LOADW(v1b, Whh1 + (size_t)(r + 128) * HH + q * 16, 4);
#undef LOADW

#define PIN(arr, n)                                                  \
    _Pragma("unroll")                                                \
    for (int _i = 0; _i < (n); ++_i) asm volatile("" : "+v"(arr[_i]))

    if (tid < G4) {
        bs0s[tid] = bih0[tid] + bhh0[tid];
        bs1s[tid] = bih1[tid] + bhh1[tid];
        h0s[tid >> 6][tid & 63] = 0.f;
        h1s[tid >> 6][tid & 63] = 0.f;
    }

    // x staging: thread (q, r) loads x[b0+q][t][r] each step; 2-step prefetch
    const float* xrow = x + ((size_t)(b0 + q) * TT) * II + r;
    xs[0][q][r] = xrow[0];
    float pre = xrow[II];                // t = 1

    // combine-stage ownership (tid < 256): cell state lives in these registers
    const int cb = tid >> 6, cj = tid & 63;
    float c0 = 0.f, c1 = 0.f;

    __syncthreads();

    // 3 barriers per step; hazard pairs all cross >=1 barrier (zp0/zp1 are
    // distinct buffers, xs double-buffered; stage-4 writes only h1s which is
    // next read in stage-3 after bar1+bar2).
    for (int t = 0; t < TT; ++t) {
        const int cur = t & 1, nxt = (t + 1) & 1;

        // re-pin every iteration: bans AGPR offload of the weight file
        PIN(w0a, 16); PIN(w0b, 16);
        PIN(h0a, 8);  PIN(h0b, 8);
        PIN(u1a, 8);  PIN(u1b, 8);
        PIN(v1a, 8);  PIN(v1b, 8);

        // ---- stage 1: layer-0 partial GEMV (reads xs[cur], h0s; writes zp0) ----
        {
            f2 aA[NB], aB[NB];
            #pragma unroll
            for (int b = 0; b < NB; ++b) { aA[b] = (f2){0.f, 0.f}; aB[b] = (f2){0.f, 0.f}; }
            #pragma unroll
            for (int b = 0; b < NB; ++b) {
                const f4* xv = (const f4*)&xs[cur][b][q * 32];
                #pragma unroll
                for (int k = 0; k < 8; ++k) {
                    f4 v = xv[k];                       // wave-uniform -> LDS broadcast
                    f2 lo = (f2){v.x, v.y}, hi = (f2){v.z, v.w};
                    aA[b] += w0a[2*k] * lo;  aA[b] += w0a[2*k+1] * hi;
                    aB[b] += w0b[2*k] * lo;  aB[b] += w0b[2*k+1] * hi;
                }
                const f4* hv = (const f4*)&h0s[b][q * 16];
                #pragma unroll
                for (int k = 0; k < 4; ++k) {
                    f4 v = hv[k];
                    f2 lo = (f2){v.x, v.y}, hi = (f2){v.z, v.w};
                    aA[b] += h0a[2*k] * lo;  aA[b] += h0a[2*k+1] * hi;
                    aB[b] += h0b[2*k] * lo;  aB[b] += h0b[2*k+1] * hi;
                }
            }
            #pragma unroll
            for (int b = 0; b < NB; ++b) {
                zp0[q][b][r]       = aA[b].x + aA[b].y;
                zp0[q][b][r + 128] = aB[b].x + aB[b].y;
            }
        }
        __syncthreads();   // bar1

        // ---- stage 2: layer-0 combine + activation + cell update (tid<256) ----
        if (tid < G4) {
            float zi = zp0[0][cb][cj]     + zp0[1][cb][cj]     + zp0[2][cb][cj]     + zp0[3][cb][cj]     + bs0s[cj];
            float zf = zp0[0][cb][64+cj]  + zp0[1][cb][64+cj]  + zp0[2][cb][64+cj]  + zp0[3][cb][64+cj]  + bs0s[64+cj];
            float zg = zp0[0][cb][128+cj] + zp0[1][cb][128+cj] + zp0[2][cb][128+cj] + zp0[3][cb][128+cj] + bs0s[128+cj];
            float zo = zp0[0][cb][192+cj] + zp0[1][cb][192+cj] + zp0[2][cb][192+cj] + zp0[3][cb][192+cj] + bs0s[192+cj];
            float gi = sigm(zi), gf = sigm(zf), gg = tanh_f(zg), go = sigm(zo);
            c0 = gf * c0 + gi * gg;
            h0s[cb][cj] = go * tanh_f(c0);
        }
        __syncthreads();   // bar2

        // ---- stage 3: layer-1 partial GEMV + x staging for t+1 ----
        {
            f2 aA[NB], aB[NB];
            #pragma unroll
            for (int b = 0; b < NB; ++b) { aA[b] = (f2){0.f, 0.f}; aB[b] = (f2){0.f, 0.f}; }
            #pragma unroll
            for (int b = 0; b < NB; ++b) {
                const f4* hv0 = (const f4*)&h0s[b][q * 16];
                #pragma unroll
                for (int k = 0; k < 4; ++k) {
                    f4 v = hv0[k];
                    f2 lo = (f2){v.x, v.y}, hi = (f2){v.z, v.w};
                    aA[b] += u1a[2*k] * lo;  aA[b] += u1a[2*k+1] * hi;
                    aB[b] += u1b[2*k] * lo;  aB[b] += u1b[2*k+1] * hi;
                }
                const f4* hv1 = (const f4*)&h1s[b][q * 16];
                #pragma unroll
                for (int k = 0; k < 4; ++k) {
                    f4 v = hv1[k];
                    f2 lo = (f2){v.x, v.y}, hi = (f2){v.z, v.w};
                    aA[b] += v1a[2*k] * lo;  aA[b] += v1a[2*k+1] * hi;
                    aB[b] += v1b[2*k] * lo;  aB[b] += v1b[2*k+1] * hi;
                }
            }
            #pragma unroll
            for (int b = 0; b < NB; ++b) {
                zp1[q][b][r]       = aA[b].x + aA[b].y;
                zp1[q][b][r + 128] = aB[b].x + aB[b].y;
            }
        }
        xs[nxt][q][r] = pre;
        {
            int tn = (t + 2 < TT) ? t + 2 : TT - 1;
            pre = xrow[(size_t)tn * II];
        }
        __syncthreads();   // bar3

        // ---- stage 4: layer-1 combine + cell update (tid<256), no barrier ----
        if (tid < G4) {
            float zi = zp1[0][cb][cj]     + zp1[1][cb][cj]     + zp1[2][cb][cj]     + zp1[3][cb][cj]     + bs1s[cj];
            float zf = zp1[0][cb][64+cj]  + zp1[1][cb][64+cj]  + zp1[2][cb][64+cj]  + zp1[3][cb][64+cj]  + bs1s[64+cj];
            float zg = zp1[0][cb][128+cj] + zp1[1][cb][128+cj] + zp1[2][cb][128+cj] + zp1[3][cb][128+cj] + bs1s[128+cj];
            float zo = zp1[0][cb][192+cj] + zp1[1][cb][192+cj] + zp1[2][cb][192+cj] + zp1[3][cb][192+cj] + bs1s[192+cj];
            float gi = sigm(zi), gf = sigm(zf), gg = tanh_f(zg), go = sigm(zo);
            c1 = gf * c1 + gi * gg;
            h1s[cb][cj] = go * tanh_f(c1);
        }
    }
#undef PIN

    // stage-4 thread wrote h1s[cb][cj] itself -> read-own-write, no barrier
    if (tid < G4) hlast[(size_t)(b0 + cb) * HH + cj] = h1s[cb][cj];
}

// MLP head: one block per batch row. relu(hW_p^T+b) -> relu(.W_1^T+b) -> .W_2^T+b
__global__ __launch_bounds__(128, 4)
void head_kernel(const float* __restrict__ hlast,
                 const float* __restrict__ Wp, const float* __restrict__ bp,
                 const float* __restrict__ W1, const float* __restrict__ b1,
                 const float* __restrict__ W2, const float* __restrict__ b2,
                 float* __restrict__ out)
{
    __shared__ float hv[HH];
    __shared__ float emb[EE];
    __shared__ float hid[EE];
    const int b = blockIdx.x;
    const int e = threadIdx.x;   // 0..127
    if (e < HH) hv[e] = hlast[(size_t)b * HH + e];
    __syncthreads();
    float z = bp[e];
    #pragma unroll
    for (int j = 0; j < HH; ++j) z += Wp[e * HH + j] * hv[j];
    emb[e] = fmaxf(z, 0.f);
    __syncthreads();
    z = b1[e];
    #pragma unroll
    for (int j = 0; j < EE; ++j) z += W1[e * EE + j] * emb[j];
    hid[e] = fmaxf(z, 0.f);
    __syncthreads();
    if (e < CC) {
        z = b2[e];
        #pragma unroll
        for (int j = 0; j < EE; ++j) z += W2[e * EE + j] * hid[j];
        out[(size_t)b * CC + e] = z;
    }
}

extern "C" void kernel_launch(void* const* d_in, const int* in_sizes, int n_in,
                              void* d_out, int out_size, void* d_ws, size_t ws_size,
                              hipStream_t stream)
{
    const float* x    = (const float*)d_in[0];
    const float* Wih0 = (const float*)d_in[1];
    const float* Whh0 = (const float*)d_in[2];
    const float* bih0 = (const float*)d_in[3];
    const float* bhh0 = (const float*)d_in[4];
    const float* Wih1 = (const float*)d_in[5];
    const float* Whh1 = (const float*)d_in[6];
    const float* bih1 = (const float*)d_in[7];
    const float* bhh1 = (const float*)d_in[8];
    const float* Wp   = (const float*)d_in[9];
    const float* bp   = (const float*)d_in[10];
    const float* W1   = (const float*)d_in[11];
    const float* b1   = (const float*)d_in[12];
    const float* W2   = (const float*)d_in[13];
    const float* b2   = (const float*)d_in[14];

    float* hlast = (float*)d_ws;           // 1024*64 fp32 = 256 KB
    float* out   = (float*)d_out;          // [1024, 100] fp32

    lstm2_persistent<<<BB / NB, NTH, 0, stream>>>(x, Wih0, Whh0, bih0, bhh0,
                                                  Wih1, Whh1, bih1, bhh1, hlast);
    head_kernel<<<BB, EE, 0, stream>>>(hlast, Wp, bp, W1, b1, W2, b2, out);
}